// Round 3
// baseline (17937.958 us; speedup 1.0000x reference)
//
#include <hip/hip_runtime.h>
#include <cstdint>

constexpr int BB = 128;   // batch
constexpr int SS = 512;   // source length
constexpr int DD = 512;   // hidden dim
constexpr int TT = 64;    // decode steps
constexpr int OO = 3;     // output dim

constexpr float C2LE = 2.8853900817779268f;  // 2*log2(e)

typedef __attribute__((ext_vector_type(8))) short bf16x8;
typedef __attribute__((ext_vector_type(4))) float f32x4;

__device__ __forceinline__ float tanh_fast(float x) {
  float e = __expf(2.0f * x);
  return 1.0f - 2.0f / (e + 1.0f);
}
__device__ __forceinline__ float sigmoid_fast(float x) {
  return 1.0f / (1.0f + __expf(-x));
}
__device__ __forceinline__ unsigned short f2bf(float f) {
  uint32_t u = __float_as_uint(f);
  uint32_t r = (u + 0x7FFFu + ((u >> 16) & 1u)) >> 16;  // RNE
  return (unsigned short)r;
}
__device__ __forceinline__ float bf2f(unsigned short h) {
  return __uint_as_float((uint32_t)h << 16);
}
__device__ __forceinline__ float2 bfx2(uint32_t u) {
  float2 r;
  r.x = __uint_as_float(u << 16);
  r.y = __uint_as_float(u & 0xFFFF0000u);
  return r;
}
__device__ __forceinline__ float fexp2(float x) {
#if __has_builtin(__builtin_amdgcn_exp2f)
  return __builtin_amdgcn_exp2f(x);
#else
  return exp2f(x);
#endif
}
__device__ __forceinline__ float frcp(float x) {
#if __has_builtin(__builtin_amdgcn_rcpf)
  return __builtin_amdgcn_rcpf(x);
#else
  return 1.0f / x;
#endif
}

// ---------------------------------------------------------------------------
// MFMA bf16 GEMM: Uk2 = bf16( C2LE * (e_bf @ Ua_bf^T + bu) )   [B*S x D]
// ---------------------------------------------------------------------------
__global__ __launch_bounds__(256) void gemm_uk_mfma(
    const unsigned short* __restrict__ A, const unsigned short* __restrict__ Bw,
    const float* __restrict__ bias, unsigned short* __restrict__ Uk) {
  __shared__ unsigned short Asb[128 * 40];
  __shared__ unsigned short Bsb[128 * 40];
  const int tid = threadIdx.x;
  const int m0 = blockIdx.y * 128, n0 = blockIdx.x * 128;
  const int w = tid >> 6, l = tid & 63;
  const int wr = w >> 1, wc = w & 1;
  const int lm = l & 15, kg = l >> 4;

  f32x4 acc[4][4] = {};

  for (int kc = 0; kc < 512; kc += 32) {
    uint4 av[2], bv[2];
#pragma unroll
    for (int p = 0; p < 2; ++p) {
      int u = tid + p * 256;
      int r = u >> 2, ko = (u & 3) * 8;
      av[p] = *(const uint4*)(A + (size_t)(m0 + r) * 512 + kc + ko);
      bv[p] = *(const uint4*)(Bw + (size_t)(n0 + r) * 512 + kc + ko);
    }
    __syncthreads();
#pragma unroll
    for (int p = 0; p < 2; ++p) {
      int u = tid + p * 256;
      int r = u >> 2, ko = (u & 3) * 8;
      *(uint4*)&Asb[r * 40 + ko] = av[p];
      *(uint4*)&Bsb[r * 40 + ko] = bv[p];
    }
    __syncthreads();
    bf16x8 af[4], bfr[4];
#pragma unroll
    for (int i = 0; i < 4; ++i) {
      af[i]  = *(const bf16x8*)&Asb[(wr * 64 + i * 16 + lm) * 40 + kg * 8];
      bfr[i] = *(const bf16x8*)&Bsb[(wc * 64 + i * 16 + lm) * 40 + kg * 8];
    }
#pragma unroll
    for (int i = 0; i < 4; ++i)
#pragma unroll
      for (int j = 0; j < 4; ++j)
        acc[i][j] = __builtin_amdgcn_mfma_f32_16x16x32_bf16(af[i], bfr[j],
                                                            acc[i][j], 0, 0, 0);
  }

  const int row_base = m0 + wr * 64;
  const int col_base = n0 + wc * 64;
#pragma unroll
  for (int j = 0; j < 4; ++j) {
    const int col = col_base + j * 16 + lm;
    const float bu = bias[col];
#pragma unroll
    for (int i = 0; i < 4; ++i) {
      const int r0 = row_base + i * 16 + kg * 4;
#pragma unroll
      for (int rr = 0; rr < 4; ++rr)
        Uk[(size_t)(r0 + rr) * 512 + col] = f2bf(C2LE * (acc[i][j][rr] + bu));
    }
  }
}

// fp32 -> bf16, 8 elems/thread
__global__ __launch_bounds__(256) void conv_bf(const float* __restrict__ in,
                                               unsigned short* __restrict__ outp) {
  size_t idx = ((size_t)blockIdx.x * 256 + threadIdx.x) * 8;
  const float4* p = (const float4*)(in + idx);
  float4 a = p[0], b = p[1];
  uint4 r;
  r.x = f2bf(a.x) | ((uint32_t)f2bf(a.y) << 16);
  r.y = f2bf(a.z) | ((uint32_t)f2bf(a.w) << 16);
  r.z = f2bf(b.x) | ((uint32_t)f2bf(b.y) << 16);
  r.w = f2bf(b.z) | ((uint32_t)f2bf(b.w) << 16);
  *(uint4*)(outp + idx) = r;
}

// Wq2[j][k] = bf16(C2LE * Wa[j][k])   (512x512)
__global__ void prep_wq2(const float* __restrict__ Wa,
                         unsigned short* __restrict__ Wq2) {
  int idx = blockIdx.x * 256 + threadIdx.x;  // 512*512
  Wq2[idx] = f2bf(C2LE * Wa[idx]);
}

// Wih3[row'][k], row' = dgrp*48 + gate*16 + dl  <-  W_ih[gate*512+dgrp*16+dl][k]
__global__ void prep_wih3(const float* __restrict__ W_ih,
                          unsigned short* __restrict__ Wih3) {
  int idx = blockIdx.x * 256 + threadIdx.x;  // 1536*512
  int rp = idx >> 9, k = idx & 511;
  int dgrp = rp / 48, rem = rp % 48;
  int g = rem >> 4, dl = rem & 15;
  int src = g * 512 + dgrp * 16 + dl;
  Wih3[idx] = f2bf(W_ih[(size_t)src * (DD + OO) + k]);
}

// Whh3 same layout from W_hh (ld 512)
__global__ void prep_whh3(const float* __restrict__ Whh,
                          unsigned short* __restrict__ Whh3) {
  int idx = blockIdx.x * 256 + threadIdx.x;  // 1536*512
  int rp = idx >> 9, k = idx & 511;
  int dgrp = rp / 48, rem = rp % 48;
  int g = rem >> 4, dl = rem & 15;
  int src = g * 512 + dgrp * 16 + dl;
  Whh3[idx] = f2bf(Whh[(size_t)src * DD + k]);
}

__global__ void prep_bq(const float* __restrict__ ba, float* __restrict__ bq) {
  int j = blockIdx.x * 256 + threadIdx.x;  // 512
  bq[j] = C2LE * ba[j];
}

// ---------------------------------------------------------------------------
// Two-level grid barrier. bars layout (uint32):
//   [g*32] for g in 0..7 : group arrive counters (128 B apart)
//   [256]                : release word
// Zeroed by hipMemsetAsync before launch; epochs monotonically increase.
// ---------------------------------------------------------------------------
__device__ __forceinline__ void gridbar(unsigned int* bars, int blk,
                                        unsigned int bc) {
  __syncthreads();
  if (threadIdx.x == 0) {
    __threadfence();
    __hip_atomic_fetch_add(bars + (blk & 7) * 32, 1u, __ATOMIC_RELEASE,
                           __HIP_MEMORY_SCOPE_AGENT);
    unsigned int* rel = bars + 256;
    if (blk == 0) {
#pragma unroll 1
      for (int g = 0; g < 8; ++g) {
        while (__hip_atomic_load(bars + g * 32, __ATOMIC_ACQUIRE,
                                 __HIP_MEMORY_SCOPE_AGENT) < bc * 32u)
          __builtin_amdgcn_s_sleep(4);
      }
      __hip_atomic_store(rel, bc, __ATOMIC_RELEASE, __HIP_MEMORY_SCOPE_AGENT);
    } else {
      while (__hip_atomic_load(rel, __ATOMIC_ACQUIRE,
                               __HIP_MEMORY_SCOPE_AGENT) < bc)
        __builtin_amdgcn_s_sleep(4);
    }
  }
  __syncthreads();
}

// ---------------------------------------------------------------------------
// Cooperative decode: 256 blocks x 1024 threads, whole T-loop in one kernel.
// Phases per step (4 grid barriers):
//  P_A  [blk 128..143]: q2 = (h_hi|h_lo) @ Wq2 + bq        (MFMA, 32 cols/blk)
//  P_B1 [all, (shalf,b)]: scores' own 256 s -> sc_s, local (m,l) -> statsg
//  P_B2 [all]: finalize softmax, write attn, ctx-partial -> ctxp[b][shalf]
//  P_D  [blk 0..127 = (mh,dgrp)]: gi = ctx@Wih3, gh = h@Whh3 (dual-A MFMA),
//        GRU in-register -> h (out_hT) + h2 hi/lo
// ---------------------------------------------------------------------------
__global__ __launch_bounds__(1024) void decode_coop(
    const unsigned short* __restrict__ Uk2, const unsigned short* __restrict__ e_bf,
    const unsigned short* __restrict__ Wq2, const unsigned short* __restrict__ Wih3,
    const unsigned short* __restrict__ Whh3, const float* __restrict__ bq,
    unsigned short* __restrict__ h2g, float* __restrict__ q2g,
    float* __restrict__ ctxp, float* __restrict__ statsg,
    unsigned int* __restrict__ bars, const float* __restrict__ e_last,
    const float* __restrict__ target, const float* __restrict__ Va_w,
    const float* __restrict__ W_ih, const float* __restrict__ b_ih,
    const float* __restrict__ b_hh, const float* __restrict__ W_out,
    const float* __restrict__ b_out, float* __restrict__ out_d,
    float* __restrict__ out_hT, float* __restrict__ out_attn) {
  const int blk = blockIdx.x, tid = threadIdx.x;
  const int w = tid >> 6, l = tid & 63, lm = l & 15, kg = l >> 4;
  const int shalf = blk >> 7, b_att = blk & 127;
  unsigned int bc = 0;

  __shared__ __align__(16) char smem[43520];  // phase union
  __shared__ float va_s[528];  // quarter-padded, persistent
  __shared__ float sc_s[256];  // local-half logits (persist B1->B2)
  __shared__ float w_s[256];
  __shared__ float red_s[32];

  // ---- init: h = e_last (fp32 master in out_hT, hi/lo pair in h2g); va cache
  if (tid < 256) {
    int idx = blk * 256 + tid;
    int b = idx >> 9, d = idx & 511;
    float v = e_last[idx];
    out_hT[idx] = v;
    unsigned short hi = f2bf(v);
    h2g[(size_t)b * 1024 + d] = hi;
    h2g[(size_t)b * 1024 + 512 + d] = f2bf(v - bf2f(hi));
  }
  if (tid < 512) va_s[(tid >> 7) * 132 + (tid & 127)] = Va_w[tid];

  // P_D per-lane constant preloads (d fixed per lane for whole kernel)
  float wx[3][3], pbih[3], pbhh[3];
  if (blk < 128 && w < 2) {
    const int d = (blk & 31) * 16 + lm;
#pragma unroll
    for (int g = 0; g < 3; ++g) {
      const float* wp = W_ih + (size_t)(g * 512 + d) * (DD + OO) + DD;
      wx[g][0] = wp[0]; wx[g][1] = wp[1]; wx[g][2] = wp[2];
      pbih[g] = b_ih[g * 512 + d];
      pbhh[g] = b_hh[g * 512 + d];
    }
  }
  gridbar(bars, blk, ++bc);

  for (int t = 0; t < TT; ++t) {
    // ================= P_A: q2 GEMM (16 blocks x 32 cols) =================
    if (blk >= 128 && blk < 144) {
      const int n0 = (blk - 128) * 32;
      const int mi = w >> 1, jt = w & 1;
      unsigned short* As = (unsigned short*)smem;          // [128][136]
      unsigned short* Bs = (unsigned short*)(smem + 34816); // [32][136]
      f32x4 acc = {};
      for (int kc = 0; kc < 1024; kc += 128) {
#pragma unroll
        for (int p = 0; p < 2; ++p) {
          int u = tid + p * 1024;
          int r = u >> 4, ko = (u & 15) * 8;
          *(uint4*)&As[r * 136 + ko] =
              *(const uint4*)&h2g[(size_t)r * 1024 + kc + ko];
        }
        if (tid < 512) {
          int r = tid >> 4, ko = (tid & 15) * 8;
          *(uint4*)&Bs[r * 136 + ko] =
              *(const uint4*)&Wq2[(size_t)(n0 + r) * 512 + (kc & 511) + ko];
        }
        __syncthreads();
#pragma unroll
        for (int ks = 0; ks < 4; ++ks) {
          bf16x8 af = *(const bf16x8*)&As[(mi * 16 + lm) * 136 + ks * 32 + kg * 8];
          bf16x8 bf_ = *(const bf16x8*)&Bs[(jt * 16 + lm) * 136 + ks * 32 + kg * 8];
          acc = __builtin_amdgcn_mfma_f32_16x16x32_bf16(af, bf_, acc, 0, 0, 0);
        }
        __syncthreads();
      }
      const int col = n0 + jt * 16 + lm;
      const float bias = bq[col];
#pragma unroll
      for (int rr = 0; rr < 4; ++rr) {
        const int b = mi * 16 + kg * 4 + rr;
        q2g[(size_t)b * 512 + col] = acc[rr] + bias;
      }
    }
    gridbar(bars, blk, ++bc);

    // ================= P_B1: scores own 256 s + local stats ================
    {
      float* qv = (float*)smem;  // 4*132 floats
      if (tid < 512) qv[(tid >> 7) * 132 + (tid & 127)] = q2g[(size_t)b_att * 512 + tid];
      __syncthreads();
      const int sl = tid >> 2, qp = tid & 3;
      {
        const int s = shalf * 256 + sl;
        const uint4* up = (const uint4*)(Uk2 + ((size_t)b_att * SS + s) * DD + qp * 128);
        const float* qb = &qv[qp * 132];
        const float* vb = &va_s[qp * 132];
        float acc = 0.f;
#pragma unroll 4
        for (int j = 0; j < 16; ++j) {
          uint4 u = up[j];
          float4 q0 = *(const float4*)&qb[j * 8], q1 = *(const float4*)&qb[j * 8 + 4];
          float4 v0 = *(const float4*)&vb[j * 8], v1 = *(const float4*)&vb[j * 8 + 4];
          float2 e0 = bfx2(u.x), e1 = bfx2(u.y), e2 = bfx2(u.z), e3 = bfx2(u.w);
          acc += v0.x * frcp(1.f + fexp2(q0.x + e0.x));
          acc += v0.y * frcp(1.f + fexp2(q0.y + e0.y));
          acc += v0.z * frcp(1.f + fexp2(q0.z + e1.x));
          acc += v0.w * frcp(1.f + fexp2(q0.w + e1.y));
          acc += v1.x * frcp(1.f + fexp2(q1.x + e2.x));
          acc += v1.y * frcp(1.f + fexp2(q1.y + e2.y));
          acc += v1.z * frcp(1.f + fexp2(q1.z + e3.x));
          acc += v1.w * frcp(1.f + fexp2(q1.w + e3.y));
        }
        acc += __shfl_xor(acc, 1);
        acc += __shfl_xor(acc, 2);
        if (qp == 0) sc_s[sl] = -2.f * acc;
      }
      __syncthreads();
      float y = (tid < 256) ? sc_s[tid] : -3.0e38f;
      float m = y;
#pragma unroll
      for (int off = 32; off; off >>= 1) m = fmaxf(m, __shfl_xor(m, off));
      if ((tid & 63) == 0) red_s[tid >> 6] = m;
      __syncthreads();
      float gm = red_s[0];
#pragma unroll
      for (int i = 1; i < 16; ++i) gm = fmaxf(gm, red_s[i]);
      float e = (tid < 256) ? __expf(y - gm) : 0.f;
      float sm = e;
#pragma unroll
      for (int off = 32; off; off >>= 1) sm += __shfl_xor(sm, off);
      if ((tid & 63) == 0) red_s[16 + (tid >> 6)] = sm;
      __syncthreads();
      if (tid == 0) {
        float tot = red_s[16];
#pragma unroll
        for (int i = 1; i < 16; ++i) tot += red_s[16 + i];
        statsg[b_att * 32 + shalf * 2] = gm;
        statsg[b_att * 32 + shalf * 2 + 1] = tot;
      }
    }
    gridbar(bars, blk, ++bc);

    // ================= P_B2: softmax finalize + ctx partial ================
    {
      float* part = (float*)smem;  // [16][520]
      const float m0 = statsg[b_att * 32 + 0], l0 = statsg[b_att * 32 + 1];
      const float m1 = statsg[b_att * 32 + 2], l1 = statsg[b_att * 32 + 3];
      const float M = fmaxf(m0, m1);
      const float invZ = frcp(l0 * __expf(m0 - M) + l1 * __expf(m1 - M));
      if (tid < 256) {
        float wv = __expf(sc_s[tid] - M) * invZ;
        w_s[tid] = wv;
        out_attn[((size_t)b_att * TT + t) * SS + shalf * 256 + tid] = wv;
      }
      __syncthreads();
      {
        const int dsl = tid & 63, sg = tid >> 6;
        const unsigned short* eb =
            e_bf + ((size_t)b_att * SS + shalf * 256 + sg * 16) * DD + dsl * 8;
        float a0 = 0.f, a1 = 0.f, a2 = 0.f, a3 = 0.f;
        float a4 = 0.f, a5 = 0.f, a6 = 0.f, a7 = 0.f;
#pragma unroll 4
        for (int si = 0; si < 16; ++si) {
          uint4 u = *(const uint4*)(eb + (size_t)si * DD);
          float ws = w_s[sg * 16 + si];
          float2 p0 = bfx2(u.x), p1 = bfx2(u.y), p2 = bfx2(u.z), p3 = bfx2(u.w);
          a0 += ws * p0.x; a1 += ws * p0.y;
          a2 += ws * p1.x; a3 += ws * p1.y;
          a4 += ws * p2.x; a5 += ws * p2.y;
          a6 += ws * p3.x; a7 += ws * p3.y;
        }
        float4 lo = {a0, a1, a2, a3}, hi = {a4, a5, a6, a7};
        *(float4*)&part[sg * 520 + dsl * 8] = lo;
        *(float4*)&part[sg * 520 + dsl * 8 + 4] = hi;
      }
      __syncthreads();
      if (tid < 512) {
        float r = 0.f;
#pragma unroll
        for (int sg = 0; sg < 16; ++sg) r += part[sg * 520 + tid];
        ctxp[((size_t)b_att * 2 + shalf) * 512 + tid] = r;
      } else if (tid < 704 && shalf == 0 && t > 0) {
        const int o = (tid - 512) >> 6, ln = tid & 63;
        const float* wrow = W_out + (size_t)o * DD;
        const float* hp = out_hT + (size_t)b_att * DD;
        float acc = 0.f;
        for (int i = ln; i < DD; i += 64) acc += hp[i] * wrow[i];
#pragma unroll
        for (int off = 32; off; off >>= 1) acc += __shfl_xor(acc, off);
        if (ln == 0) out_d[((size_t)b_att * TT + (t - 1)) * OO + o] = acc + b_out[o];
      }
    }
    gridbar(bars, blk, ++bc);

    // ========= P_D: dual GEMM (gi from ctx, gh from h) + GRU ==============
    if (blk < 128) {
      const int mh = blk >> 5, dgrp = blk & 31;
      unsigned short* Ach = (unsigned short*)smem;       // ctx_hi [32][72]
      unsigned short* Acl = Ach + 32 * 72;               // ctx_lo
      unsigned short* Ahh = Acl + 32 * 72;               // h_hi
      unsigned short* Ahl = Ahh + 32 * 72;               // h_lo
      unsigned short* Bih = Ahl + 32 * 72;               // [48][72]
      unsigned short* Bhh = Bih + 48 * 72;               // [48][72]
      f32x4 aci[3] = {};
      f32x4 agh[3] = {};
      for (int kc = 0; kc < 512; kc += 64) {
        if (tid < 256) {  // ctx combine + hi/lo split: 8 elems/thread
          int r = tid >> 3, ko = (tid & 7) * 8;
          int b = mh * 32 + r;
          const float* p0 = &ctxp[((size_t)b * 2) * 512 + kc + ko];
          const float* p1 = &ctxp[((size_t)b * 2 + 1) * 512 + kc + ko];
          float4 a0 = *(const float4*)p0, a1 = *(const float4*)(p0 + 4);
          float4 c0 = *(const float4*)p1, c1 = *(const float4*)(p1 + 4);
          float v[8] = {a0.x + c0.x, a0.y + c0.y, a0.z + c0.z, a0.w + c0.w,
                        a1.x + c1.x, a1.y + c1.y, a1.z + c1.z, a1.w + c1.w};
          uint32_t H[4], L[4];
#pragma unroll
          for (int i = 0; i < 4; ++i) {
            unsigned short h0 = f2bf(v[2 * i]), h1 = f2bf(v[2 * i + 1]);
            unsigned short l0_ = f2bf(v[2 * i] - bf2f(h0));
            unsigned short l1_ = f2bf(v[2 * i + 1] - bf2f(h1));
            H[i] = (uint32_t)h0 | ((uint32_t)h1 << 16);
            L[i] = (uint32_t)l0_ | ((uint32_t)l1_ << 16);
          }
          *(uint4*)&Ach[r * 72 + ko] = *(uint4*)H;
          *(uint4*)&Acl[r * 72 + ko] = *(uint4*)L;
        } else if (tid < 512) {  // h hi/lo copy
          int u = tid - 256;
          int r = u >> 3, ko = (u & 7) * 8;
          int b = mh * 32 + r;
          *(uint4*)&Ahh[r * 72 + ko] =
              *(const uint4*)&h2g[(size_t)b * 1024 + kc + ko];
          *(uint4*)&Ahl[r * 72 + ko] =
              *(const uint4*)&h2g[(size_t)b * 1024 + 512 + kc + ko];
        } else if (tid < 896) {  // B slices
          int u = tid - 512;
          int r = u >> 3, ko = (u & 7) * 8;  // r < 48
          *(uint4*)&Bih[r * 72 + ko] =
              *(const uint4*)&Wih3[(size_t)(dgrp * 48 + r) * 512 + kc + ko];
          *(uint4*)&Bhh[r * 72 + ko] =
              *(const uint4*)&Whh3[(size_t)(dgrp * 48 + r) * 512 + kc + ko];
        }
        __syncthreads();
        if (w < 2) {
#pragma unroll
          for (int ks = 0; ks < 2; ++ks) {
            const int ao = (w * 16 + lm) * 72 + ks * 32 + kg * 8;
            bf16x8 ach_ = *(const bf16x8*)&Ach[ao];
            bf16x8 acl_ = *(const bf16x8*)&Acl[ao];
            bf16x8 ahh_ = *(const bf16x8*)&Ahh[ao];
            bf16x8 ahl_ = *(const bf16x8*)&Ahl[ao];
#pragma unroll
            for (int g = 0; g < 3; ++g) {
              const int bo = (g * 16 + lm) * 72 + ks * 32 + kg * 8;
              bf16x8 bi = *(const bf16x8*)&Bih[bo];
              bf16x8 bh = *(const bf16x8*)&Bhh[bo];
              aci[g] = __builtin_amdgcn_mfma_f32_16x16x32_bf16(ach_, bi, aci[g], 0, 0, 0);
              aci[g] = __builtin_amdgcn_mfma_f32_16x16x32_bf16(acl_, bi, aci[g], 0, 0, 0);
              agh[g] = __builtin_amdgcn_mfma_f32_16x16x32_bf16(ahh_, bh, agh[g], 0, 0, 0);
              agh[g] = __builtin_amdgcn_mfma_f32_16x16x32_bf16(ahl_, bh, agh[g], 0, 0, 0);
            }
          }
        }
        __syncthreads();
      }
      if (w < 2) {
        const int d = dgrp * 16 + lm;
#pragma unroll
        for (int rr = 0; rr < 4; ++rr) {
          const int b = mh * 32 + w * 16 + kg * 4 + rr;
          float x0 = 0.f, x1 = 0.f, x2 = 0.f;
          if (t > 0) {
            const float* xp = target + ((size_t)b * TT + (t - 1)) * OO;
            x0 = xp[0]; x1 = xp[1]; x2 = xp[2];
          }
          float ir = aci[0][rr] + pbih[0] + x0 * wx[0][0] + x1 * wx[0][1] + x2 * wx[0][2];
          float iz = aci[1][rr] + pbih[1] + x0 * wx[1][0] + x1 * wx[1][1] + x2 * wx[1][2];
          float in_ = aci[2][rr] + pbih[2] + x0 * wx[2][0] + x1 * wx[2][1] + x2 * wx[2][2];
          float hr = agh[0][rr] + pbhh[0];
          float hz = agh[1][rr] + pbhh[1];
          float hn = agh[2][rr] + pbhh[2];
          float r_ = sigmoid_fast(ir + hr);
          float z_ = sigmoid_fast(iz + hz);
          float n_ = tanh_fast(in_ + r_ * hn);
          float hold = out_hT[(size_t)b * DD + d];
          float hnew = (1.f - z_) * n_ + z_ * hold;
          out_hT[(size_t)b * DD + d] = hnew;
          unsigned short hhi = f2bf(hnew);
          h2g[(size_t)b * 1024 + d] = hhi;
          h2g[(size_t)b * 1024 + 512 + d] = f2bf(hnew - bf2f(hhi));
        }
      }
    }
    gridbar(bars, blk, ++bc);
  }

  // ---- tail: out_d[:, T-1] from final h
  if (blk < 128 && tid < 192) {
    const int b = blk;
    const int o = tid >> 6, ln = tid & 63;
    const float* wrow = W_out + (size_t)o * DD;
    const float* hp = out_hT + (size_t)b * DD;
    float acc = 0.f;
    for (int i = ln; i < DD; i += 64) acc += hp[i] * wrow[i];
#pragma unroll
    for (int off = 32; off; off >>= 1) acc += __shfl_xor(acc, off);
    if (ln == 0) out_d[((size_t)b * TT + (TT - 1)) * OO + o] = acc + b_out[o];
  }
}

// ---------------------------------------------------------------------------
extern "C" void kernel_launch(void* const* d_in, const int* in_sizes, int n_in,
                              void* d_out, int out_size, void* d_ws, size_t ws_size,
                              hipStream_t stream) {
  const float* e_all  = (const float*)d_in[0];
  const float* e_last = (const float*)d_in[1];
  const float* target = (const float*)d_in[2];
  const float* Wa     = (const float*)d_in[3];
  const float* ba     = (const float*)d_in[4];
  const float* Ua     = (const float*)d_in[5];
  const float* bu     = (const float*)d_in[6];
  const float* Va_w   = (const float*)d_in[7];
  const float* W_ih   = (const float*)d_in[9];
  const float* b_ih   = (const float*)d_in[10];
  const float* W_hh   = (const float*)d_in[11];
  const float* b_hh   = (const float*)d_in[12];
  const float* W_out  = (const float*)d_in[13];
  const float* b_out  = (const float*)d_in[14];

  float* out      = (float*)d_out;
  float* out_d    = out;                         // [B,T,3]
  float* out_hT   = out + (size_t)BB * TT * OO;  // [1,B,D]  (live h)
  float* out_attn = out_hT + (size_t)BB * DD;    // [B,T,S]

  // Workspace layout (138,956,800 B <= 139,479,040 B proven-safe):
  //   0           Uk2     67,108,864
  //   67,108,864  e_bf    67,108,864
  //   134,217,728 Wq2        524,288   [512][512] bf16
  //   134,742,016 Wih3     1,572,864   [1536][512] bf16
  //   136,314,880 Whh3     1,572,864
  //   137,887,744 bq           2,048
  //   137,889,792 h2         262,144   [128][1024] bf16 (hi|lo)  } Ua_bf
  //   138,151,936 q2g        262,144   [128][512] f32            } alias
  //   138,414,080 ctxp       524,288   [128][2][512] f32
  //   138,938,368 statsg      16,384   [128][32] f32 (padded)
  //   138,954,752 bars         2,048
  char* wsB = (char*)d_ws;
  unsigned short* Uk2   = (unsigned short*)wsB;
  unsigned short* e_bfp = (unsigned short*)(wsB + 67108864);
  unsigned short* Wq2   = (unsigned short*)(wsB + 134217728);
  unsigned short* Wih3  = (unsigned short*)(wsB + 134742016);
  unsigned short* Whh3  = (unsigned short*)(wsB + 136314880);
  float* bq             = (float*)(wsB + 137887744);
  unsigned short* h2    = (unsigned short*)(wsB + 137889792);
  float* q2g            = (float*)(wsB + 138151936);
  float* ctxp           = (float*)(wsB + 138414080);
  float* statsg         = (float*)(wsB + 138938368);
  unsigned int* bars    = (unsigned int*)(wsB + 138954752);
  unsigned short* Ua_bf = (unsigned short*)(wsB + 137889792);  // prologue alias

  prep_wq2<<<(DD * DD) / 256, 256, 0, stream>>>(Wa, Wq2);
  prep_wih3<<<(1536 * 512) / 256, 256, 0, stream>>>(W_ih, Wih3);
  prep_whh3<<<(1536 * 512) / 256, 256, 0, stream>>>(W_hh, Whh3);
  prep_bq<<<2, 256, 0, stream>>>(ba, bq);
  conv_bf<<<(BB * SS * DD) / (8 * 256), 256, 0, stream>>>(e_all, e_bfp);
  conv_bf<<<(DD * DD) / (8 * 256), 256, 0, stream>>>(Ua, Ua_bf);
  gemm_uk_mfma<<<dim3(DD / 128, (BB * SS) / 128), 256, 0, stream>>>(
      e_bfp, Ua_bf, bu, Uk2);

  hipMemsetAsync(bars, 0, 2048, stream);

  void* kargs[] = {
      (void*)&Uk2,    (void*)&e_bfp,  (void*)&Wq2,    (void*)&Wih3,
      (void*)&Whh3,   (void*)&bq,     (void*)&h2,     (void*)&q2g,
      (void*)&ctxp,   (void*)&statsg, (void*)&bars,   (void*)&e_last,
      (void*)&target, (void*)&Va_w,   (void*)&W_ih,   (void*)&b_ih,
      (void*)&b_hh,   (void*)&W_out,  (void*)&b_out,  (void*)&out_d,
      (void*)&out_hT, (void*)&out_attn};
  hipLaunchCooperativeKernel((void*)decode_coop, dim3(256), dim3(1024), kargs,
                             0, stream);
}

// Round 4
// 5481.314 us; speedup vs baseline: 3.2726x; 3.2726x over previous
//
#include <hip/hip_runtime.h>
#include <cstdint>

constexpr int BB = 128;   // batch
constexpr int SS = 512;   // source length
constexpr int DD = 512;   // hidden dim
constexpr int TT = 64;    // decode steps
constexpr int OO = 3;     // output dim

constexpr float C2LE = 2.8853900817779268f;  // 2*log2(e)

typedef __attribute__((ext_vector_type(8))) short bf16x8;
typedef __attribute__((ext_vector_type(4))) float f32x4;

__device__ __forceinline__ float tanh_fast(float x) {
  float e = __expf(2.0f * x);
  return 1.0f - 2.0f / (e + 1.0f);
}
__device__ __forceinline__ float sigmoid_fast(float x) {
  return 1.0f / (1.0f + __expf(-x));
}
__device__ __forceinline__ unsigned short f2bf(float f) {
  uint32_t u = __float_as_uint(f);
  uint32_t r = (u + 0x7FFFu + ((u >> 16) & 1u)) >> 16;  // RNE
  return (unsigned short)r;
}
__device__ __forceinline__ float bf2f(unsigned short h) {
  return __uint_as_float((uint32_t)h << 16);
}
__device__ __forceinline__ float2 bfx2(uint32_t u) {
  float2 r;
  r.x = __uint_as_float(u << 16);
  r.y = __uint_as_float(u & 0xFFFF0000u);
  return r;
}
__device__ __forceinline__ float fexp2(float x) {
#if __has_builtin(__builtin_amdgcn_exp2f)
  return __builtin_amdgcn_exp2f(x);
#else
  return exp2f(x);
#endif
}
__device__ __forceinline__ float frcp(float x) {
#if __has_builtin(__builtin_amdgcn_rcpf)
  return __builtin_amdgcn_rcpf(x);
#else
  return 1.0f / x;
#endif
}

// ---------------------------------------------------------------------------
// MFMA bf16 GEMM: Uk2 = bf16( C2LE * (e_bf @ Ua_bf^T + bu) )   [B*S x D]
// ---------------------------------------------------------------------------
__global__ __launch_bounds__(256) void gemm_uk_mfma(
    const unsigned short* __restrict__ A, const unsigned short* __restrict__ Bw,
    const float* __restrict__ bias, unsigned short* __restrict__ Uk) {
  __shared__ unsigned short Asb[128 * 40];
  __shared__ unsigned short Bsb[128 * 40];
  const int tid = threadIdx.x;
  const int m0 = blockIdx.y * 128, n0 = blockIdx.x * 128;
  const int w = tid >> 6, l = tid & 63;
  const int wr = w >> 1, wc = w & 1;
  const int lm = l & 15, kg = l >> 4;

  f32x4 acc[4][4] = {};

  for (int kc = 0; kc < 512; kc += 32) {
    uint4 av[2], bv[2];
#pragma unroll
    for (int p = 0; p < 2; ++p) {
      int u = tid + p * 256;
      int r = u >> 2, ko = (u & 3) * 8;
      av[p] = *(const uint4*)(A + (size_t)(m0 + r) * 512 + kc + ko);
      bv[p] = *(const uint4*)(Bw + (size_t)(n0 + r) * 512 + kc + ko);
    }
    __syncthreads();
#pragma unroll
    for (int p = 0; p < 2; ++p) {
      int u = tid + p * 256;
      int r = u >> 2, ko = (u & 3) * 8;
      *(uint4*)&Asb[r * 40 + ko] = av[p];
      *(uint4*)&Bsb[r * 40 + ko] = bv[p];
    }
    __syncthreads();
    bf16x8 af[4], bfr[4];
#pragma unroll
    for (int i = 0; i < 4; ++i) {
      af[i]  = *(const bf16x8*)&Asb[(wr * 64 + i * 16 + lm) * 40 + kg * 8];
      bfr[i] = *(const bf16x8*)&Bsb[(wc * 64 + i * 16 + lm) * 40 + kg * 8];
    }
#pragma unroll
    for (int i = 0; i < 4; ++i)
#pragma unroll
      for (int j = 0; j < 4; ++j)
        acc[i][j] = __builtin_amdgcn_mfma_f32_16x16x32_bf16(af[i], bfr[j],
                                                            acc[i][j], 0, 0, 0);
  }

  const int row_base = m0 + wr * 64;
  const int col_base = n0 + wc * 64;
#pragma unroll
  for (int j = 0; j < 4; ++j) {
    const int col = col_base + j * 16 + lm;
    const float bu = bias[col];
#pragma unroll
    for (int i = 0; i < 4; ++i) {
      const int r0 = row_base + i * 16 + kg * 4;
#pragma unroll
      for (int rr = 0; rr < 4; ++rr)
        Uk[(size_t)(r0 + rr) * 512 + col] = f2bf(C2LE * (acc[i][j][rr] + bu));
    }
  }
}

// fp32 -> bf16, 8 elems/thread
__global__ __launch_bounds__(256) void conv_bf(const float* __restrict__ in,
                                               unsigned short* __restrict__ outp) {
  size_t idx = ((size_t)blockIdx.x * 256 + threadIdx.x) * 8;
  const float4* p = (const float4*)(in + idx);
  float4 a = p[0], b = p[1];
  uint4 r;
  r.x = f2bf(a.x) | ((uint32_t)f2bf(a.y) << 16);
  r.y = f2bf(a.z) | ((uint32_t)f2bf(a.w) << 16);
  r.z = f2bf(b.x) | ((uint32_t)f2bf(b.y) << 16);
  r.w = f2bf(b.z) | ((uint32_t)f2bf(b.w) << 16);
  *(uint4*)(outp + idx) = r;
}

// Wq2[j][k] = bf16(C2LE * Wa[j][k])   (512x512)
__global__ void prep_wq2(const float* __restrict__ Wa,
                         unsigned short* __restrict__ Wq2) {
  int idx = blockIdx.x * 256 + threadIdx.x;  // 512*512
  Wq2[idx] = f2bf(C2LE * Wa[idx]);
}

// Wih3[row'][k], row' = dgrp*48 + gate*16 + dl  <-  W_ih[gate*512+dgrp*16+dl][k]
__global__ void prep_wih3(const float* __restrict__ W_ih,
                          unsigned short* __restrict__ Wih3) {
  int idx = blockIdx.x * 256 + threadIdx.x;  // 1536*512
  int rp = idx >> 9, k = idx & 511;
  int dgrp = rp / 48, rem = rp % 48;
  int g = rem >> 4, dl = rem & 15;
  int src = g * 512 + dgrp * 16 + dl;
  Wih3[idx] = f2bf(W_ih[(size_t)src * (DD + OO) + k]);
}

// Whh3 same layout from W_hh (ld 512)
__global__ void prep_whh3(const float* __restrict__ Whh,
                          unsigned short* __restrict__ Whh3) {
  int idx = blockIdx.x * 256 + threadIdx.x;  // 1536*512
  int rp = idx >> 9, k = idx & 511;
  int dgrp = rp / 48, rem = rp % 48;
  int g = rem >> 4, dl = rem & 15;
  int src = g * 512 + dgrp * 16 + dl;
  Whh3[idx] = f2bf(Whh[(size_t)src * DD + k]);
}

__global__ void prep_bq(const float* __restrict__ ba, float* __restrict__ bq) {
  int j = blockIdx.x * 256 + threadIdx.x;  // 512
  bq[j] = C2LE * ba[j];
}

// init: h = e_last -> out_hT (f32 master) + h2 (bf16 hi|lo)
__global__ void init_h(const float* __restrict__ e_last,
                       float* __restrict__ out_hT,
                       unsigned short* __restrict__ h2g) {
  int idx = blockIdx.x * 256 + threadIdx.x;  // 128*512
  int b = idx >> 9, d = idx & 511;
  float v = e_last[idx];
  out_hT[idx] = v;
  unsigned short hi = f2bf(v);
  h2g[(size_t)b * 1024 + d] = hi;
  h2g[(size_t)b * 1024 + 512 + d] = f2bf(v - bf2f(hi));
}

// ---------------------------------------------------------------------------
// K0: q2 = (h_hi|h_lo) @ Wq2^T + bq  (blocks 0..15, MFMA, 32 cols each)
//     block 16: out_d[:, t-1] = h @ W_out^T + b_out   (f32, from out_hT)
// ---------------------------------------------------------------------------
__global__ __launch_bounds__(1024) void qgemm_out(
    const unsigned short* __restrict__ h2g, const unsigned short* __restrict__ Wq2,
    const float* __restrict__ bq, float* __restrict__ q2g,
    const float* __restrict__ out_hT, const float* __restrict__ W_out,
    const float* __restrict__ b_out, float* __restrict__ out_d, int t) {
  const int blk = blockIdx.x, tid = threadIdx.x;
  __shared__ unsigned short As[128 * 136];
  __shared__ unsigned short Bs[32 * 136];
  if (blk < 16) {
    const int w = tid >> 6, l = tid & 63, lm = l & 15, kg = l >> 4;
    const int n0 = blk * 32;
    const int mi = w >> 1, jt = w & 1;
    f32x4 acc = {};
    for (int kc = 0; kc < 1024; kc += 128) {
#pragma unroll
      for (int p = 0; p < 2; ++p) {
        int u = tid + p * 1024;
        int r = u >> 4, ko = (u & 15) * 8;
        *(uint4*)&As[r * 136 + ko] =
            *(const uint4*)&h2g[(size_t)r * 1024 + kc + ko];
      }
      if (tid < 512) {
        int r = tid >> 4, ko = (tid & 15) * 8;
        *(uint4*)&Bs[r * 136 + ko] =
            *(const uint4*)&Wq2[(size_t)(n0 + r) * 512 + (kc & 511) + ko];
      }
      __syncthreads();
#pragma unroll
      for (int ks = 0; ks < 4; ++ks) {
        bf16x8 af = *(const bf16x8*)&As[(mi * 16 + lm) * 136 + ks * 32 + kg * 8];
        bf16x8 bf_ = *(const bf16x8*)&Bs[(jt * 16 + lm) * 136 + ks * 32 + kg * 8];
        acc = __builtin_amdgcn_mfma_f32_16x16x32_bf16(af, bf_, acc, 0, 0, 0);
      }
      __syncthreads();
    }
    const int col = n0 + jt * 16 + lm;
    const float bias = bq[col];
#pragma unroll
    for (int rr = 0; rr < 4; ++rr) {
      const int b = mi * 16 + kg * 4 + rr;
      q2g[(size_t)b * 512 + col] = acc[rr] + bias;
    }
  } else if (t > 0) {
    const int b = tid >> 3, g8 = tid & 7;
    const float* hp = out_hT + (size_t)b * DD + g8 * 64;
#pragma unroll
    for (int o = 0; o < OO; ++o) {
      const float* wrow = W_out + (size_t)o * DD + g8 * 64;
      float acc = 0.f;
#pragma unroll 8
      for (int i = 0; i < 64; ++i) acc += hp[i] * wrow[i];
      acc += __shfl_down(acc, 4, 8);
      acc += __shfl_down(acc, 2, 8);
      acc += __shfl_down(acc, 1, 8);
      if (g8 == 0) out_d[((size_t)b * TT + (t - 1)) * OO + o] = acc + b_out[o];
    }
  }
}

// ---------------------------------------------------------------------------
// K1: scores[b,s] = -2 * sum_d va[d] / (1 + 2^(q2[d]+Uk2[b,s,d]))
//     (true score = const - 2*S; const cancels in softmax)  grid (8,B) x 256
// ---------------------------------------------------------------------------
__global__ __launch_bounds__(256) void attn_scores(
    const unsigned short* __restrict__ Uk2, const float* __restrict__ q2g,
    const float* __restrict__ va, float* __restrict__ scores) {
  const int b = blockIdx.y;
  const int s0 = blockIdx.x * 64;
  __shared__ float4 shq[DD / 4];
  __shared__ float4 shva[DD / 4];
  const int tid = threadIdx.x;
  if (tid < DD / 4) {
    shq[tid] = ((const float4*)(q2g + (size_t)b * DD))[tid];
    shva[tid] = ((const float4*)va)[tid];
  }
  __syncthreads();
  const int g = tid >> 4, l = tid & 15;
#pragma unroll
  for (int i = 0; i < 4; ++i) {
    const int s = s0 + 16 * i + g;
    const uint4* row = (const uint4*)(Uk2 + ((size_t)b * SS + s) * DD);
    float acc = 0.f;
#pragma unroll
    for (int jj = 0; jj < 4; ++jj) {
      const int slot = l + 16 * jj;       // uint4 index 0..63
      uint4 u = row[slot];
      float4 q0 = shq[slot * 2], q1 = shq[slot * 2 + 1];
      float4 v0 = shva[slot * 2], v1 = shva[slot * 2 + 1];
      float2 e0 = bfx2(u.x), e1 = bfx2(u.y), e2 = bfx2(u.z), e3 = bfx2(u.w);
      acc += v0.x * frcp(1.f + fexp2(q0.x + e0.x));
      acc += v0.y * frcp(1.f + fexp2(q0.y + e0.y));
      acc += v0.z * frcp(1.f + fexp2(q0.z + e1.x));
      acc += v0.w * frcp(1.f + fexp2(q0.w + e1.y));
      acc += v1.x * frcp(1.f + fexp2(q1.x + e2.x));
      acc += v1.y * frcp(1.f + fexp2(q1.y + e2.y));
      acc += v1.z * frcp(1.f + fexp2(q1.z + e3.x));
      acc += v1.w * frcp(1.f + fexp2(q1.w + e3.y));
    }
#pragma unroll
    for (int off = 8; off; off >>= 1) acc += __shfl_down(acc, off, 16);
    if (l == 0) scores[(size_t)b * SS + s] = -2.f * acc;
  }
}

// ---------------------------------------------------------------------------
// K2: softmax(scores[b]) -> w ; ctx[b, 128-d chunk] = w . e_bf ; grid (4,B).
// ---------------------------------------------------------------------------
__global__ __launch_bounds__(256) void attn_ctx(
    const unsigned short* __restrict__ e_bf, const float* __restrict__ scores,
    float* __restrict__ ctx, float* __restrict__ attn_out, int t) {
  const int b = blockIdx.y, dc = blockIdx.x;
  __shared__ float w[SS];
  __shared__ float red[8];
  __shared__ float part[16][132];  // [sg][sl*8+c], pitch 132
  const int tid = threadIdx.x;

  float v0 = scores[(size_t)b * SS + tid];
  float v1 = scores[(size_t)b * SS + 256 + tid];
  float m = fmaxf(v0, v1);
#pragma unroll
  for (int off = 32; off; off >>= 1) m = fmaxf(m, __shfl_xor(m, off));
  if ((tid & 63) == 0) red[tid >> 6] = m;
  __syncthreads();
  m = fmaxf(fmaxf(red[0], red[1]), fmaxf(red[2], red[3]));
  float e0 = __expf(v0 - m), e1 = __expf(v1 - m);
  float ss = e0 + e1;
#pragma unroll
  for (int off = 32; off; off >>= 1) ss += __shfl_xor(ss, off);
  __syncthreads();
  if ((tid & 63) == 0) red[tid >> 6] = ss;
  __syncthreads();
  const float inv = 1.f / (red[0] + red[1] + red[2] + red[3]);
  float w0 = e0 * inv, w1 = e1 * inv;
  w[tid] = w0;
  w[tid + 256] = w1;
  if (dc == 0) {
    float* ao = attn_out + ((size_t)b * TT + t) * SS;
    ao[tid] = w0;
    ao[tid + 256] = w1;
  }
  __syncthreads();

  {
    const int sl = tid & 15, sg = tid >> 4;
    const unsigned short* eb = e_bf + (size_t)b * SS * DD + dc * 128 + sl * 8;
    float a0 = 0.f, a1 = 0.f, a2 = 0.f, a3 = 0.f;
    float a4 = 0.f, a5 = 0.f, a6 = 0.f, a7 = 0.f;
    for (int s = sg * 32; s < sg * 32 + 32; ++s) {
      uint4 u = *(const uint4*)(eb + (size_t)s * DD);
      float ws = w[s];
      float2 p0 = bfx2(u.x), p1 = bfx2(u.y), p2 = bfx2(u.z), p3 = bfx2(u.w);
      a0 += ws * p0.x; a1 += ws * p0.y;
      a2 += ws * p1.x; a3 += ws * p1.y;
      a4 += ws * p2.x; a5 += ws * p2.y;
      a6 += ws * p3.x; a7 += ws * p3.y;
    }
    float* pr = &part[sg][sl * 8];
    pr[0] = a0; pr[1] = a1; pr[2] = a2; pr[3] = a3;
    pr[4] = a4; pr[5] = a5; pr[6] = a6; pr[7] = a7;
  }
  __syncthreads();
  if (tid < 128) {
    const int sl = tid >> 3, c = tid & 7;
    float r = 0.f;
#pragma unroll
    for (int sg = 0; sg < 16; ++sg) r += part[sg][sl * 8 + c];
    ctx[(size_t)b * DD + dc * 128 + sl * 8 + c] = r;
  }
}

// ---------------------------------------------------------------------------
// K3: gi = ctx @ Wih3, gh = h @ Whh3 (dual hi/lo MFMA), GRU pointwise.
// grid 128 = (mh 0..3) x (dgrp 0..31): 32 b x 16 d per block.
// ---------------------------------------------------------------------------
__global__ __launch_bounds__(1024) void gru_fused(
    const float* __restrict__ ctx, unsigned short* __restrict__ h2g,
    const unsigned short* __restrict__ Wih3, const unsigned short* __restrict__ Whh3,
    float* __restrict__ out_hT, const float* __restrict__ target,
    const float* __restrict__ W_ih, const float* __restrict__ b_ih,
    const float* __restrict__ b_hh, int t) {
  const int blk = blockIdx.x, tid = threadIdx.x;
  const int w = tid >> 6, l = tid & 63, lm = l & 15, kg = l >> 4;
  const int mh = blk >> 5, dgrp = blk & 31;

  __shared__ unsigned short Ach[32 * 72];
  __shared__ unsigned short Acl[32 * 72];
  __shared__ unsigned short Ahh[32 * 72];
  __shared__ unsigned short Ahl[32 * 72];
  __shared__ unsigned short Bih[48 * 72];
  __shared__ unsigned short Bhh[48 * 72];

  float wx[3][3], pbih[3], pbhh[3];
  if (w < 2) {
    const int d = dgrp * 16 + lm;
#pragma unroll
    for (int g = 0; g < 3; ++g) {
      const float* wp = W_ih + (size_t)(g * 512 + d) * (DD + OO) + DD;
      wx[g][0] = wp[0]; wx[g][1] = wp[1]; wx[g][2] = wp[2];
      pbih[g] = b_ih[g * 512 + d];
      pbhh[g] = b_hh[g * 512 + d];
    }
  }

  f32x4 aci[3] = {};
  f32x4 agh[3] = {};
  for (int kc = 0; kc < 512; kc += 64) {
    if (tid < 256) {  // ctx hi/lo split: 8 elems/thread
      int r = tid >> 3, ko = (tid & 7) * 8;
      int b = mh * 32 + r;
      const float* p0 = &ctx[(size_t)b * 512 + kc + ko];
      float4 a0 = *(const float4*)p0, a1 = *(const float4*)(p0 + 4);
      float v[8] = {a0.x, a0.y, a0.z, a0.w, a1.x, a1.y, a1.z, a1.w};
      uint32_t H[4], L[4];
#pragma unroll
      for (int i = 0; i < 4; ++i) {
        unsigned short h0 = f2bf(v[2 * i]), h1 = f2bf(v[2 * i + 1]);
        unsigned short l0_ = f2bf(v[2 * i] - bf2f(h0));
        unsigned short l1_ = f2bf(v[2 * i + 1] - bf2f(h1));
        H[i] = (uint32_t)h0 | ((uint32_t)h1 << 16);
        L[i] = (uint32_t)l0_ | ((uint32_t)l1_ << 16);
      }
      *(uint4*)&Ach[r * 72 + ko] = *(uint4*)H;
      *(uint4*)&Acl[r * 72 + ko] = *(uint4*)L;
    } else if (tid < 512) {  // h hi/lo copy
      int u = tid - 256;
      int r = u >> 3, ko = (u & 7) * 8;
      int b = mh * 32 + r;
      *(uint4*)&Ahh[r * 72 + ko] =
          *(const uint4*)&h2g[(size_t)b * 1024 + kc + ko];
      *(uint4*)&Ahl[r * 72 + ko] =
          *(const uint4*)&h2g[(size_t)b * 1024 + 512 + kc + ko];
    } else if (tid < 896) {  // B slices
      int u = tid - 512;
      int r = u >> 3, ko = (u & 7) * 8;  // r < 48
      *(uint4*)&Bih[r * 72 + ko] =
          *(const uint4*)&Wih3[(size_t)(dgrp * 48 + r) * 512 + kc + ko];
      *(uint4*)&Bhh[r * 72 + ko] =
          *(const uint4*)&Whh3[(size_t)(dgrp * 48 + r) * 512 + kc + ko];
    }
    __syncthreads();
    if (w < 2) {
#pragma unroll
      for (int ks = 0; ks < 2; ++ks) {
        const int ao = (w * 16 + lm) * 72 + ks * 32 + kg * 8;
        bf16x8 ach_ = *(const bf16x8*)&Ach[ao];
        bf16x8 acl_ = *(const bf16x8*)&Acl[ao];
        bf16x8 ahh_ = *(const bf16x8*)&Ahh[ao];
        bf16x8 ahl_ = *(const bf16x8*)&Ahl[ao];
#pragma unroll
        for (int g = 0; g < 3; ++g) {
          const int bo = (g * 16 + lm) * 72 + ks * 32 + kg * 8;
          bf16x8 bi = *(const bf16x8*)&Bih[bo];
          bf16x8 bh = *(const bf16x8*)&Bhh[bo];
          aci[g] = __builtin_amdgcn_mfma_f32_16x16x32_bf16(ach_, bi, aci[g], 0, 0, 0);
          aci[g] = __builtin_amdgcn_mfma_f32_16x16x32_bf16(acl_, bi, aci[g], 0, 0, 0);
          agh[g] = __builtin_amdgcn_mfma_f32_16x16x32_bf16(ahh_, bh, agh[g], 0, 0, 0);
          agh[g] = __builtin_amdgcn_mfma_f32_16x16x32_bf16(ahl_, bh, agh[g], 0, 0, 0);
        }
      }
    }
    __syncthreads();
  }

  if (w < 2) {
    const int d = dgrp * 16 + lm;
#pragma unroll
    for (int rr = 0; rr < 4; ++rr) {
      const int b = mh * 32 + w * 16 + kg * 4 + rr;
      float x0 = 0.f, x1 = 0.f, x2 = 0.f;
      if (t > 0) {
        const float* xp = target + ((size_t)b * TT + (t - 1)) * OO;
        x0 = xp[0]; x1 = xp[1]; x2 = xp[2];
      }
      float ir = aci[0][rr] + pbih[0] + x0 * wx[0][0] + x1 * wx[0][1] + x2 * wx[0][2];
      float iz = aci[1][rr] + pbih[1] + x0 * wx[1][0] + x1 * wx[1][1] + x2 * wx[1][2];
      float in_ = aci[2][rr] + pbih[2] + x0 * wx[2][0] + x1 * wx[2][1] + x2 * wx[2][2];
      float hr = agh[0][rr] + pbhh[0];
      float hz = agh[1][rr] + pbhh[1];
      float hn = agh[2][rr] + pbhh[2];
      float r_ = sigmoid_fast(ir + hr);
      float z_ = sigmoid_fast(iz + hz);
      float n_ = tanh_fast(in_ + r_ * hn);
      float hold = out_hT[(size_t)b * DD + d];
      float hnew = (1.f - z_) * n_ + z_ * hold;
      out_hT[(size_t)b * DD + d] = hnew;
      unsigned short hhi = f2bf(hnew);
      h2g[(size_t)b * 1024 + d] = hhi;
      h2g[(size_t)b * 1024 + 512 + d] = f2bf(hnew - bf2f(hhi));
    }
  }
}

// ---------------------------------------------------------------------------
extern "C" void kernel_launch(void* const* d_in, const int* in_sizes, int n_in,
                              void* d_out, int out_size, void* d_ws, size_t ws_size,
                              hipStream_t stream) {
  const float* e_all  = (const float*)d_in[0];
  const float* e_last = (const float*)d_in[1];
  const float* target = (const float*)d_in[2];
  const float* Wa     = (const float*)d_in[3];
  const float* ba     = (const float*)d_in[4];
  const float* Ua     = (const float*)d_in[5];
  const float* bu     = (const float*)d_in[6];
  const float* Va_w   = (const float*)d_in[7];
  const float* W_ih   = (const float*)d_in[9];
  const float* b_ih   = (const float*)d_in[10];
  const float* W_hh   = (const float*)d_in[11];
  const float* b_hh   = (const float*)d_in[12];
  const float* W_out  = (const float*)d_in[13];
  const float* b_out  = (const float*)d_in[14];

  float* out      = (float*)d_out;
  float* out_d    = out;                         // [B,T,3]
  float* out_hT   = out + (size_t)BB * TT * OO;  // [1,B,D]  (live h, f32)
  float* out_attn = out_hT + (size_t)BB * DD;    // [B,T,S]

  // Workspace layout (138,938,368 B <= 139,479,040 B proven-safe):
  //   0           Uk2     67,108,864
  //   67,108,864  e_bf    67,108,864
  //   134,217,728 Wq2        524,288   [512][512] bf16
  //   134,742,016 Wih3     1,572,864   [1536][512] bf16
  //   136,314,880 Whh3     1,572,864
  //   137,887,744 bq           2,048
  //   137,889,792 h2         262,144   [128][1024] bf16 (hi|lo)  } Ua_bf
  //   138,151,936 q2g        262,144   [128][512] f32            } alias
  //   138,414,080 ctx        262,144   [128][512] f32
  //   138,676,224 scores     262,144   [128][512] f32
  char* wsB = (char*)d_ws;
  unsigned short* Uk2   = (unsigned short*)wsB;
  unsigned short* e_bfp = (unsigned short*)(wsB + 67108864);
  unsigned short* Wq2   = (unsigned short*)(wsB + 134217728);
  unsigned short* Wih3  = (unsigned short*)(wsB + 134742016);
  unsigned short* Whh3  = (unsigned short*)(wsB + 136314880);
  float* bq             = (float*)(wsB + 137887744);
  unsigned short* h2    = (unsigned short*)(wsB + 137889792);
  float* q2g            = (float*)(wsB + 138151936);
  float* ctx            = (float*)(wsB + 138414080);
  float* scores         = (float*)(wsB + 138676224);
  unsigned short* Ua_bf = (unsigned short*)(wsB + 137889792);  // prologue alias

  prep_wq2<<<(DD * DD) / 256, 256, 0, stream>>>(Wa, Wq2);
  prep_wih3<<<(1536 * 512) / 256, 256, 0, stream>>>(W_ih, Wih3);
  prep_whh3<<<(1536 * 512) / 256, 256, 0, stream>>>(W_hh, Whh3);
  prep_bq<<<2, 256, 0, stream>>>(ba, bq);
  conv_bf<<<(BB * SS * DD) / (8 * 256), 256, 0, stream>>>(e_all, e_bfp);
  conv_bf<<<(DD * DD) / (8 * 256), 256, 0, stream>>>(Ua, Ua_bf);
  gemm_uk_mfma<<<dim3(DD / 128, (BB * SS) / 128), 256, 0, stream>>>(
      e_bfp, Ua_bf, bu, Uk2);
  init_h<<<(BB * DD) / 256, 256, 0, stream>>>(e_last, out_hT, h2);  // after gemm_uk (alias)

  for (int t = 0; t < TT; ++t) {
    qgemm_out<<<17, 1024, 0, stream>>>(h2, Wq2, bq, q2g, out_hT, W_out, b_out,
                                       out_d, t);
    attn_scores<<<dim3(SS / 64, BB), 256, 0, stream>>>(Uk2, q2g, Va_w, scores);
    attn_ctx<<<dim3(4, BB), 256, 0, stream>>>(e_bfp, scores, ctx, out_attn, t);
    gru_fused<<<128, 1024, 0, stream>>>(ctx, h2, Wih3, Whh3, out_hT, target,
                                        W_ih, b_ih, b_hh, t);
  }
  // final out_d[:, T-1] from h_T
  qgemm_out<<<17, 1024, 0, stream>>>(h2, Wq2, bq, q2g, out_hT, W_out, b_out,
                                     out_d, TT);
}